// Round 4
// baseline (541.482 us; speedup 1.0000x reference)
//
#include <hip/hip_runtime.h>
#include <stdint.h>

typedef unsigned short u16;
typedef __attribute__((ext_vector_type(8))) short short8;   // 8 x bf16 MFMA operand
typedef __attribute__((ext_vector_type(4))) float f32x4;    // MFMA accumulator
typedef __attribute__((ext_vector_type(4))) uint32_t u32x4;

#define KEXP   8
#define LATENT 256
#define CONDD  1024
#define HID    128
#define EIN    1281
#define EINP   1344   // 21*64, zero padded
#define NCH    21
#define NTOT   1024   // KEXP*HID
#define BROWS  32768

__device__ __forceinline__ u16 f2bf(float x) {              // RNE fp32->bf16
  uint32_t v = __float_as_uint(x);
  v += 0x7fffu + ((v >> 16) & 1u);
  return (u16)(v >> 16);
}

__device__ __forceinline__ void async16(const void* g, void* l) {
  __builtin_amdgcn_global_load_lds(
      (const __attribute__((address_space(1))) void*)g,
      (__attribute__((address_space(3))) void*)l, 16, 0, 0);
}

__device__ __forceinline__ float silu(float x) { return x / (1.f + __expf(-x)); }

// ---------------------------------------------------------------------------
// prep: (a) 32x32 LDS-tiled weight transposes -> bf16  (blocks 0..1727)
//       (b) X = [u | cond | tau | 0] -> bf16 Xb[32768][1344]  (blocks 1728..)
// ---------------------------------------------------------------------------
#define W1_TILES (KEXP * 42 * 4)    // 1344
#define W2_TILES (KEXP * 4 * 4)     // 128
#define W3_TILES (KEXP * 4 * 8)     // 256
#define CONVB    (W1_TILES + W2_TILES + W3_TILES)   // 1728
#define XCONVB   2688               // 32768*168 groups / 256 threads / 8 per thread

__global__ void prep(const float* __restrict__ W1, const float* __restrict__ W2,
                     const float* __restrict__ W3,
                     const float* __restrict__ cond, const float* __restrict__ uu,
                     const float* __restrict__ tau,
                     u16* __restrict__ W1t, u16* __restrict__ W2t,
                     u16* __restrict__ W3t2, u16* __restrict__ Xb) {
  __shared__ float t[32][33];
  const int bid = blockIdx.x;
  if (bid < CONVB) {
    const int tx = threadIdx.x & 31, ty = threadIdx.x >> 5;   // 32 x 8
    if (bid < W1_TILES) {
      int k = bid / 168, r = bid % 168;
      int d0 = (r / 4) * 32, h0 = (r % 4) * 32;
      const float* src = W1 + (size_t)k * EIN * HID;
      #pragma unroll
      for (int s = 0; s < 4; ++s) {
        int d = d0 + ty + s * 8;
        t[ty + s * 8][tx] = (d < EIN) ? src[(size_t)d * HID + h0 + tx] : 0.f;
      }
      __syncthreads();
      u16* dst = W1t + (size_t)k * HID * EINP;
      #pragma unroll
      for (int s = 0; s < 4; ++s)
        dst[(size_t)(h0 + ty + s * 8) * EINP + d0 + tx] = f2bf(t[tx][ty + s * 8]);
    } else if (bid < W1_TILES + W2_TILES) {
      int j = bid - W1_TILES;
      int k = j / 16, r = j % 16;
      int d0 = (r / 4) * 32, h0 = (r % 4) * 32;
      const float* src = W2 + (size_t)k * HID * HID;
      #pragma unroll
      for (int s = 0; s < 4; ++s)
        t[ty + s * 8][tx] = src[(size_t)(d0 + ty + s * 8) * HID + h0 + tx];
      __syncthreads();
      u16* dst = W2t + (size_t)k * HID * HID;
      #pragma unroll
      for (int s = 0; s < 4; ++s)
        dst[(size_t)(h0 + ty + s * 8) * HID + d0 + tx] = f2bf(t[tx][ty + s * 8]);
    } else {
      int j = bid - W1_TILES - W2_TILES;
      int k = j / 32, r = j % 32;
      int d0 = (r / 8) * 32, h0 = (r % 8) * 32;   // d=g(128), h=l(256)
      const float* src = W3 + (size_t)k * HID * LATENT;
      #pragma unroll
      for (int s = 0; s < 4; ++s)
        t[ty + s * 8][tx] = src[(size_t)(d0 + ty + s * 8) * LATENT + h0 + tx];
      __syncthreads();
      #pragma unroll
      for (int s = 0; s < 4; ++s)
        W3t2[(size_t)(h0 + ty + s * 8) * NTOT + k * HID + d0 + tx] = f2bf(t[tx][ty + s * 8]);
    }
    return;
  }
  // ---- X conversion: 8 groups of 8 cols per thread ----
  const int base = (bid - CONVB) * 256 + threadIdx.x;
  #pragma unroll 1
  for (int s = 0; s < 8; ++s) {
    unsigned i = (unsigned)base + (unsigned)s * (XCONVB * 256);
    unsigned row = i / 168u;
    unsigned grp = i - row * 168u;
    float f0 = 0.f, f1 = 0.f, f2 = 0.f, f3 = 0.f, f4 = 0.f, f5 = 0.f, f6 = 0.f, f7 = 0.f;
    if (grp < 32u) {
      const float4* p = (const float4*)(uu + (size_t)row * LATENT + grp * 8);
      float4 A = p[0], Bv = p[1];
      f0 = A.x; f1 = A.y; f2 = A.z; f3 = A.w; f4 = Bv.x; f5 = Bv.y; f6 = Bv.z; f7 = Bv.w;
    } else if (grp < 160u) {
      const float4* p = (const float4*)(cond + (size_t)row * CONDD + (grp - 32u) * 8);
      float4 A = p[0], Bv = p[1];
      f0 = A.x; f1 = A.y; f2 = A.z; f3 = A.w; f4 = Bv.x; f5 = Bv.y; f6 = Bv.z; f7 = Bv.w;
    } else if (grp == 160u) {
      f0 = tau[row];
    }
    u32x4 pk;
    pk[0] = (uint32_t)f2bf(f0) | ((uint32_t)f2bf(f1) << 16);
    pk[1] = (uint32_t)f2bf(f2) | ((uint32_t)f2bf(f3) << 16);
    pk[2] = (uint32_t)f2bf(f4) | ((uint32_t)f2bf(f5) << 16);
    pk[3] = (uint32_t)f2bf(f6) | ((uint32_t)f2bf(f7) << 16);
    *(u32x4*)(Xb + (size_t)row * EINP + grp * 8) = pk;
  }
}

// ---------------------------------------------------------------------------
// h1h2: per (m-tile, expert): acc = Xb @ W1t  (pure-async m97 loop, BK=64),
// then fused tail: H1 = silu(acc+b1) -> LDS; acc2 = H1 @ W2 (b-frags straight
// from L2); H[:,e*128:] = p_e * silu(acc2+b2)  (bf16).  32 KB LDS, 4 blk/CU.
// bid swizzle: the 8 expert-siblings of an m-tile stay on one XCD.
// ---------------------------------------------------------------------------
__global__ __launch_bounds__(256, 4)
void h1h2(const u16* __restrict__ Xb, const u16* __restrict__ W1t,
          const float* __restrict__ b1, const u16* __restrict__ W2t,
          const float* __restrict__ b2, const float* __restrict__ p_hat,
          u16* __restrict__ H) {
  __shared__ struct {
    union {
      struct { u16 As[128 * 64]; u16 Bs[128 * 64]; } s;  // 32 KB main loop
      u16 H1s[128 * 128];                                // 32 KB tail A
      u16 Cs[128 * 72];                                  // 18 KB epilogue half
    } u;
    float Ps[128];
  } sm;

  const int tid  = threadIdx.x;
  const int wave = tid >> 6;
  const int lane = tid & 63;
  const int q    = lane >> 4;
  const int ln   = lane & 15;
  const int wm   = wave >> 1, wn = wave & 1;
  const int bid  = blockIdx.x;
  const int mt   = ((bid >> 6) << 3) | (bid & 7);   // 0..255, same-XCD siblings
  const int e    = (bid >> 3) & 7;
  const int m0   = mt * 128;
  const u16* w1k = W1t + (size_t)e * HID * EINP;
  const u16* w2k = W2t + (size_t)e * HID * HID;

  if (tid < 128) sm.Ps[tid] = p_hat[(size_t)(m0 + tid) * KEXP + e];

  const f32x4 fz = {0.f, 0.f, 0.f, 0.f};
  f32x4 acc[4][4];
  #pragma unroll
  for (int m = 0; m < 4; ++m)
    #pragma unroll
    for (int n = 0; n < 4; ++n) acc[m][n] = fz;

  const int rloc = lane >> 3;
  const int gsw  = lane & 7;
  const int gsrc = gsw ^ rloc;

  // ================= main loop: X @ W1, 21 chunks of BK=64 =================
  #pragma unroll 1
  for (int ic = 0; ic < NCH; ++ic) {
    const int d0 = ic * 64;
    #pragma unroll
    for (int i = 0; i < 4; ++i) {
      int rbase = (wave * 4 + i) * 8;
      async16(Xb + (size_t)(m0 + rbase + rloc) * EINP + d0 + gsrc * 8,
              &sm.u.s.As[rbase * 64]);
      async16(w1k + (size_t)(rbase + rloc) * EINP + d0 + gsrc * 8,
              &sm.u.s.Bs[rbase * 64]);
    }
    __syncthreads();
    #pragma unroll
    for (int ks = 0; ks < 2; ++ks) {
      short8 a[4], b[4];
      #pragma unroll
      for (int m = 0; m < 4; ++m) {
        int r = wm * 64 + m * 16 + ln;
        int g = (ks * 4 + q) ^ (r & 7);
        a[m] = *(const short8*)(&sm.u.s.As[r * 64 + g * 8]);
      }
      #pragma unroll
      for (int n = 0; n < 4; ++n) {
        int c = wn * 64 + n * 16 + ln;
        int g = (ks * 4 + q) ^ (c & 7);
        b[n] = *(const short8*)(&sm.u.s.Bs[c * 64 + g * 8]);
      }
      #pragma unroll
      for (int m = 0; m < 4; ++m)
        #pragma unroll
        for (int n = 0; n < 4; ++n)
          acc[m][n] = __builtin_amdgcn_mfma_f32_16x16x32_bf16(a[m], b[n], acc[m][n], 0, 0, 0);
    }
    __syncthreads();
  }

  // ================= tail A: H1 = silu(acc + b1) -> LDS (16-grp swizzle) ====
  #pragma unroll
  for (int n = 0; n < 4; ++n) {
    int col = wn * 64 + n * 16 + ln;
    float bv = b1[e * HID + col];
    int g = col >> 3, off = col & 7;
    #pragma unroll
    for (int m = 0; m < 4; ++m)
      #pragma unroll
      for (int r = 0; r < 4; ++r) {
        int row = wm * 64 + m * 16 + q * 4 + r;
        sm.u.H1s[row * 128 + (g ^ (row & 15)) * 8 + off] = f2bf(silu(acc[m][n][r] + bv));
      }
  }
  __syncthreads();

  // ================= tail B: acc2 = H1 @ W2  (K=128, W2 frags from L2) =====
  f32x4 acc2[4][4];
  #pragma unroll
  for (int m = 0; m < 4; ++m)
    #pragma unroll
    for (int n = 0; n < 4; ++n) acc2[m][n] = fz;
  #pragma unroll
  for (int ks = 0; ks < 4; ++ks) {
    short8 a[4], b[4];
    #pragma unroll
    for (int n = 0; n < 4; ++n) {
      int c = wn * 64 + n * 16 + ln;                 // g-dim
      b[n] = *(const short8*)(w2k + (size_t)c * HID + ks * 32 + q * 8);
    }
    #pragma unroll
    for (int m = 0; m < 4; ++m) {
      int row = wm * 64 + m * 16 + ln;
      int g = (ks * 4 + q) ^ (row & 15);
      a[m] = *(const short8*)(&sm.u.H1s[row * 128 + g * 8]);
    }
    #pragma unroll
    for (int m = 0; m < 4; ++m)
      #pragma unroll
      for (int n = 0; n < 4; ++n)
        acc2[m][n] = __builtin_amdgcn_mfma_f32_16x16x32_bf16(a[m], b[n], acc2[m][n], 0, 0, 0);
  }
  __syncthreads();   // H1s reads done; Cs may alias

  // ================= epilogue: H = p * silu(acc2 + b2), two passes =========
  #pragma unroll 1
  for (int hf = 0; hf < 2; ++hf) {
    if (wn == hf) {
      #pragma unroll
      for (int n = 0; n < 4; ++n) {
        int cl = n * 16 + ln;
        float bv = b2[e * HID + hf * 64 + cl];
        #pragma unroll
        for (int m = 0; m < 4; ++m)
          #pragma unroll
          for (int r = 0; r < 4; ++r) {
            int row = wm * 64 + m * 16 + q * 4 + r;
            sm.u.Cs[row * 72 + cl] = f2bf(sm.Ps[row] * silu(acc2[m][n][r] + bv));
          }
      }
    }
    __syncthreads();
    #pragma unroll
    for (int i = 0; i < 4; ++i) {
      int lin = tid + i * 256;
      int row = lin >> 3;
      int grp = lin & 7;
      *(u32x4*)(H + (size_t)(m0 + row) * NTOT + e * HID + hf * 64 + grp * 8) =
          *(const u32x4*)(&sm.u.Cs[row * 72 + grp * 8]);
    }
    __syncthreads();
  }
}

// ---------------------------------------------------------------------------
// out_gemm: out = H @ W3t2^T + p @ b3. M=32768 N=256 K=1024. 128x128 tiles,
// 2x2 wave quadrants, 40 KB LDS -> 4 blk/CU. n-siblings share an XCD.
// ---------------------------------------------------------------------------
__global__ __launch_bounds__(256, 4)
void out_gemm(const u16* __restrict__ H, const float* __restrict__ p_hat,
              const u16* __restrict__ W3t2, const float* __restrict__ b3,
              float* __restrict__ out) {
  __shared__ struct {
    u16 As[128 * 64];     // 16 KB
    u16 Bs[128 * 64];     // 16 KB
    float Ps[128 * 8];    // 4 KB
    float B3s[128 * 8];   // 4 KB
  } sm;

  const int tid  = threadIdx.x;
  const int wave = tid >> 6;
  const int lane = tid & 63;
  const int q    = lane >> 4;
  const int ln   = lane & 15;
  const int wm   = wave >> 1, wn = wave & 1;
  const int bid  = blockIdx.x;
  const int mt   = ((bid >> 4) << 3) | (bid & 7);   // 0..255
  const int bn   = (bid >> 3) & 1;
  const int m0   = mt * 128, n0 = bn * 128;

  *(float4*)(&sm.Ps[tid * 4]) = *(const float4*)(p_hat + (size_t)m0 * KEXP + tid * 4);
  #pragma unroll
  for (int s = 0; s < 4; ++s) {
    int lin = tid + s * 256;
    int k = lin >> 7, c = lin & 127;
    sm.B3s[c * 8 + k] = b3[k * LATENT + n0 + c];
  }

  const f32x4 fz = {0.f, 0.f, 0.f, 0.f};
  f32x4 acc[4][4];
  #pragma unroll
  for (int m = 0; m < 4; ++m)
    #pragma unroll
    for (int n = 0; n < 4; ++n) acc[m][n] = fz;

  const int rloc = lane >> 3;
  const int gsw  = lane & 7;
  const int gsrc = gsw ^ rloc;

  #pragma unroll 1
  for (int kc = 0; kc < 16; ++kc) {
    #pragma unroll
    for (int i = 0; i < 4; ++i) {
      int rbase = (wave * 4 + i) * 8;
      async16(H + (size_t)(m0 + rbase + rloc) * NTOT + kc * 64 + gsrc * 8,
              &sm.As[rbase * 64]);
      async16(W3t2 + (size_t)(n0 + rbase + rloc) * NTOT + kc * 64 + gsrc * 8,
              &sm.Bs[rbase * 64]);
    }
    __syncthreads();
    #pragma unroll
    for (int ks = 0; ks < 2; ++ks) {
      short8 a[4], b[4];
      #pragma unroll
      for (int m = 0; m < 4; ++m) {
        int r = wm * 64 + m * 16 + ln;
        int g = (ks * 4 + q) ^ (r & 7);
        a[m] = *(const short8*)(&sm.As[r * 64 + g * 8]);
      }
      #pragma unroll
      for (int n = 0; n < 4; ++n) {
        int c = wn * 64 + n * 16 + ln;
        int g = (ks * 4 + q) ^ (c & 7);
        b[n] = *(const short8*)(&sm.Bs[c * 64 + g * 8]);
      }
      #pragma unroll
      for (int m = 0; m < 4; ++m)
        #pragma unroll
        for (int n = 0; n < 4; ++n)
          acc[m][n] = __builtin_amdgcn_mfma_f32_16x16x32_bf16(a[m], b[n], acc[m][n], 0, 0, 0);
    }
    __syncthreads();
  }

  #pragma unroll
  for (int n = 0; n < 4; ++n) {
    int col = wn * 64 + n * 16 + ln;
    float4 c0 = *(const float4*)(&sm.B3s[col * 8]);
    float4 c1 = *(const float4*)(&sm.B3s[col * 8 + 4]);
    #pragma unroll
    for (int m = 0; m < 4; ++m)
      #pragma unroll
      for (int r = 0; r < 4; ++r) {
        int row = wm * 64 + m * 16 + q * 4 + r;
        float4 p0 = *(const float4*)(&sm.Ps[row * 8]);
        float4 p1 = *(const float4*)(&sm.Ps[row * 8 + 4]);
        float v = acc[m][n][r]
                + p0.x * c0.x + p0.y * c0.y + p0.z * c0.z + p0.w * c0.w
                + p1.x * c1.x + p1.y * c1.y + p1.z * c1.z + p1.w * c1.w;
        out[(size_t)(m0 + row) * LATENT + n0 + col] = v;
      }
  }
}

extern "C" void kernel_launch(void* const* d_in, const int* in_sizes, int n_in,
                              void* d_out, int out_size, void* d_ws, size_t ws_size,
                              hipStream_t stream) {
  const float* cond  = (const float*)d_in[0];
  const float* u     = (const float*)d_in[1];
  const float* tau   = (const float*)d_in[2];
  const float* p_hat = (const float*)d_in[3];
  const float* W1    = (const float*)d_in[4];
  const float* b1    = (const float*)d_in[5];
  const float* W2    = (const float*)d_in[6];
  const float* b2    = (const float*)d_in[7];
  const float* W3    = (const float*)d_in[8];
  const float* b3    = (const float*)d_in[9];
  float* out = (float*)d_out;

  const size_t N1 = (size_t)KEXP * HID * EINP;    //  1,376,256
  const size_t N2 = (size_t)KEXP * HID * HID;     //    131,072
  const size_t N3 = (size_t)LATENT * NTOT;        //    262,144
  const size_t NX = (size_t)BROWS * EINP;         // 44,040,192 (Xb bf16)
  const size_t NH = (size_t)BROWS * NTOT;         // 33,554,432 (H bf16)
  if (ws_size < (N1 + N2 + N3 + NX + NH) * sizeof(u16)) return;  // ~159 MB

  u16* W1t  = (u16*)d_ws;
  u16* W2t  = W1t + N1;
  u16* W3t2 = W2t + N2;
  u16* Xb   = W3t2 + N3;
  u16* H    = Xb + NX;

  prep<<<CONVB + XCONVB, 256, 0, stream>>>(W1, W2, W3, cond, u, tau,
                                           W1t, W2t, W3t2, Xb);
  h1h2<<<2048, 256, 0, stream>>>(Xb, W1t, b1, W2t, b2, p_hat, H);
  out_gemm<<<512, 256, 0, stream>>>(H, p_hat, W3t2, b3, out);
}